// Round 14
// baseline (79.575 us; speedup 1.0000x reference)
//
#include <hip/hip_runtime.h>
#include <hip/hip_bf16.h>

#define NN 50000
#define NE 800000

typedef __attribute__((ext_vector_type(4))) float f32x4;
typedef __attribute__((ext_vector_type(8))) __bf16 bf16x8;

__device__ __forceinline__ float wred64(float v) {
    v += __shfl_xor(v, 32, 64);
    v += __shfl_xor(v, 16, 64);
    v += __shfl_xor(v, 8, 64);
    v += __shfl_xor(v, 4, 64);
    v += __shfl_xor(v, 2, 64);
    v += __shfl_xor(v, 1, 64);
    return v;
}

__device__ __forceinline__ float arcosh_f(float z) {
    z = fmaxf(z, 1.0f + 1e-7f);
    return logf(z + sqrtf(z * z - 1.0f));
}

// ---------------------------------------------------------------------------
// prep: pack W^T into MFMA B-fragment-linear order as bf16 hi/lo pair.
// ---------------------------------------------------------------------------
__global__ void prep_kernel(const float* __restrict__ weight, const float* __restrict__ bias,
                            ushort* __restrict__ WfHi, ushort* __restrict__ WfLo,
                            float* __restrict__ biasP) {
    int t8 = blockIdx.x * 256 + threadIdx.x;   // 0..2047 over grid of 8 blocks
    int l = t8 & 63, f = t8 >> 6;
    int t = f & 3, jt = f >> 2;
    int g = l >> 4, r = l & 15;
    int col = jt * 16 + r;
    #pragma unroll
    for (int i = 0; i < 8; ++i) {
        int k = 32 * g + 8 * t + i;
        float v = (col < 127) ? weight[col * 128 + k] : 0.0f;
        __bf16 h = (__bf16)v;
        float lo = v - (float)h;
        __bf16 lb = (__bf16)lo;
        WfHi[t8 * 8 + i] = __builtin_bit_cast(unsigned short, h);
        WfLo[t8 * 8 + i] = __builtin_bit_cast(unsigned short, lb);
    }
    if (t8 < 128) biasP[t8] = (t8 < 127) ? bias[t8] : 0.0f;
}

// ---------------------------------------------------------------------------
// rowptr[r] = first edge with row >= r (rows sorted)
// ---------------------------------------------------------------------------
__global__ void rowptr_kernel(const int* __restrict__ row, int* __restrict__ rowptr) {
    int e = blockIdx.x * 256 + threadIdx.x;
    if (e >= NE) return;
    int r1 = row[e];
    int r0 = (e == 0) ? -1 : row[e - 1];
    for (int r = r0 + 1; r <= r1; ++r) rowptr[r] = e;
    if (e == NE - 1) {
        for (int r = r1 + 1; r <= NN; ++r) rowptr[r] = NE;
    }
}

// ---------------------------------------------------------------------------
// Stage 1 via MFMA (bf16x3 compensated): h = exp_map_zero([0, W@log0(x)+b])
// Output: hhb[node][128] bf16 (slot j = tail comp j, j<127; slot 127 = 0)
//         hhead[node]    fp32 head (the precision-critical component)
// ---------------------------------------------------------------------------
__global__ __launch_bounds__(256) void transform_kernel(
        const float* __restrict__ x, const ushort* __restrict__ Wf /* hi|lo 64KB */,
        const float* __restrict__ biasP, ushort* __restrict__ hhb,
        float* __restrict__ hhead) {
    __shared__ __align__(16) ushort WF[32768];   // 64 KB: [0,16384) hi, rest lo

    const int tid = threadIdx.x;
    #pragma unroll
    for (int i = 0; i < 16; ++i)
        ((float4*)WF)[i * 256 + tid] = ((const float4*)Wf)[i * 256 + tid];

    const int lane = tid & 63, w = tid >> 6;
    const int g = lane >> 4, r = lane & 15;
    const int nodeA = blockIdx.x * 64 + w * 16 + r;   // A-fragment row

    float xv[32];
    float x0 = 1.0f;
    if (nodeA < NN) {
        const float* xp = x + (long)nodeA * 129;
        x0 = xp[0];
        __builtin_memcpy(xv, xp + 1 + 32 * g, 128);
    } else {
        #pragma unroll
        for (int i = 0; i < 32; ++i) xv[i] = 0.0f;
    }
    // input invariant: x0 = sqrt(1 + sum tail^2)  ->  ssq = x0^2 - 1
    float dist = arcosh_f(x0);
    float sc = dist / sqrtf(fmaxf(x0 * x0 - 1.0f, 1e-6f));

    bf16x8 ah[4], al[4];
    #pragma unroll
    for (int t = 0; t < 4; ++t) {
        #pragma unroll
        for (int i = 0; i < 8; ++i) {
            float v = sc * xv[8 * t + i];
            __bf16 h = (__bf16)v;
            ah[t][i] = h;
            al[t][i] = (__bf16)(v - (float)h);
        }
    }
    __syncthreads();

    f32x4 acc[8];
    #pragma unroll
    for (int jt = 0; jt < 8; ++jt) acc[jt] = (f32x4){0.0f, 0.0f, 0.0f, 0.0f};

    #pragma unroll
    for (int jt = 0; jt < 8; ++jt) {
        #pragma unroll
        for (int t = 0; t < 4; ++t) {
            const int f = jt * 4 + t;
            bf16x8 bh = *(const bf16x8*)&WF[(f * 64 + lane) * 8];
            bf16x8 bl = *(const bf16x8*)&WF[16384 + (f * 64 + lane) * 8];
            acc[jt] = __builtin_amdgcn_mfma_f32_16x16x32_bf16(al[t], bh, acc[jt], 0, 0, 0);
            acc[jt] = __builtin_amdgcn_mfma_f32_16x16x32_bf16(ah[t], bl, acc[jt], 0, 0, 0);
            acc[jt] = __builtin_amdgcn_mfma_f32_16x16x32_bf16(ah[t], bh, acc[jt], 0, 0, 0);
        }
    }

    float bv[8];
    #pragma unroll
    for (int jt = 0; jt < 8; ++jt) bv[jt] = biasP[jt * 16 + r];

    #pragma unroll
    for (int i = 0; i < 4; ++i) {
        float m[8];
        float p = 0.0f;
        #pragma unroll
        for (int jt = 0; jt < 8; ++jt) {
            m[jt] = acc[jt][i] + bv[jt];
            p = fmaf(m[jt], m[jt], p);
        }
        p += __shfl_xor(p, 1, 64);
        p += __shfl_xor(p, 2, 64);
        p += __shfl_xor(p, 4, 64);
        p += __shfl_xor(p, 8, 64);        // p = sum_{j<127} mx_j^2
        float n = sqrtf(fmaxf(p, 1e-6f));
        float rr = sinhf(fminf(n, 50.0f)) / n;
        int node = blockIdx.x * 64 + w * 16 + g * 4 + i;
        if (node < NN) {
            #pragma unroll
            for (int jt = 0; jt < 8; ++jt) {
                int j = jt * 16 + r;
                float vv = rr * m[jt];
                ushort us = (j == 127) ? (ushort)0
                          : __builtin_bit_cast(unsigned short, (__bf16)vv);
                hhb[node * 128 + j] = us;
            }
            if (r == 15) hhead[node] = sqrtf(1.0f + rr * rr * p);
        }
    }
}

// ---------------------------------------------------------------------------
// Stage 2+3 fused: segment gather-sum (bf16 rows + fp32 head), Lorentz
// centroid normalize, hyp_act. One wave per node.
// L1-transaction-minimized gather: per 8-edge step, only THREE vector-memory
// instructions touch random lines:
//   2x row gathers: lane (g=l>>4, r=l&15), slot t in {0,1}, loads dwordx4 =
//     16B = comps r*8..r*8+7 of edge e+4t+g  (4 edges per instruction);
//   1x head gather: lane handles edge e+(l&7) (8x replicated, *0.125 exact).
// col/val are SGPR-resident (uniform clamped indices -> s_loads); the
// per-lane edge choice c[4t+g] / v[4t+g] is a 4-way cndmask select from
// scalars -- the address chain is scalar-load -> select, never gather->gather
// (round 12's mistake). Pad slots (k >= m) re-read the last edge's line
// (L1-hot) with val=0. Accumulators sf[j] (comp r*8+j, edges == g mod 4)
// merged by shfl_xor(16,32); epilogue identical to round 9's (verified).
// ---------------------------------------------------------------------------
__global__ __launch_bounds__(256) void centroid_act_kernel(
        const ushort* __restrict__ hhb, const float* __restrict__ hhead,
        const float* __restrict__ val, const int* __restrict__ col,
        const int* __restrict__ rowptr, float* __restrict__ out) {
    const int lane = threadIdx.x & 63;
    const int node = __builtin_amdgcn_readfirstlane(blockIdx.x * 4 + (threadIdx.x >> 6));
    const int g = lane >> 4, r = lane & 15;
    const int lo = rowptr[node], hi = rowptr[node + 1];
    const int ls = lane & 7;

    float sf[8];
    #pragma unroll
    for (int j = 0; j < 8; ++j) sf[j] = 0.0f;
    float s0p = 0.0f;

    for (int e = lo; e < hi; e += 8) {
        const int m = hi - e;                       // uniform
        // col/val: 8 scalar loads with uniform clamped indices
        int c[8]; float v[8];
        #pragma unroll
        for (int k = 0; k < 8; ++k) {
            const int ik = (k < m) ? k : (m - 1);   // uniform -> s_cselect
            c[k] = col[e + ik];
            v[k] = (k < m) ? val[e + ik] : 0.0f;
        }
        // head path: lane's edge e+(l&7), per-lane gather (no select chain)
        {
            const int ih = (ls < m) ? ls : (m - 1);
            const int cs = col[e + ih];
            const float vs = (ls < m) ? val[e + ih] : 0.0f;
            s0p = fmaf(vs, hhead[cs], s0p);
        }
        // row path: 2 slots, each ONE dwordx4 instruction covering 4 edges
        #pragma unroll
        for (int t = 0; t < 2; ++t) {
            const int ct = (g == 0) ? c[4 * t] : (g == 1) ? c[4 * t + 1]
                         : (g == 2) ? c[4 * t + 2] : c[4 * t + 3];
            const float vt = (g == 0) ? v[4 * t] : (g == 1) ? v[4 * t + 1]
                           : (g == 2) ? v[4 * t + 2] : v[4 * t + 3];
            const uint4 u = *(const uint4*)((const char*)hhb + (((long)ct << 8) + (r << 4)));
            sf[0] = fmaf(vt, __builtin_bit_cast(float, u.x << 16), sf[0]);
            sf[1] = fmaf(vt, __builtin_bit_cast(float, u.x & 0xffff0000u), sf[1]);
            sf[2] = fmaf(vt, __builtin_bit_cast(float, u.y << 16), sf[2]);
            sf[3] = fmaf(vt, __builtin_bit_cast(float, u.y & 0xffff0000u), sf[3]);
            sf[4] = fmaf(vt, __builtin_bit_cast(float, u.z << 16), sf[4]);
            sf[5] = fmaf(vt, __builtin_bit_cast(float, u.z & 0xffff0000u), sf[5]);
            sf[6] = fmaf(vt, __builtin_bit_cast(float, u.w << 16), sf[6]);
            sf[7] = fmaf(vt, __builtin_bit_cast(float, u.w & 0xffff0000u), sf[7]);
        }
    }

    // merge the 4 edge-groups: sf[j] -> full sum for comp r*8+j (all lanes)
    #pragma unroll
    for (int j = 0; j < 8; ++j) {
        sf[j] += __shfl_xor(sf[j], 16, 64);
        sf[j] += __shfl_xor(sf[j], 32, 64);
    }
    float s0 = wred64(s0p) * 0.125f;               // each edge counted by 8 lanes

    // tsum = sum over all 127 tail comps of s_f^2 (slot 127 pad is 0)
    float p2 = 0.0f;
    #pragma unroll
    for (int j = 0; j < 8; ++j) p2 = fmaf(sf[j], sf[j], p2);
    p2 += __shfl_xor(p2, 1, 64);
    p2 += __shfl_xor(p2, 2, 64);
    p2 += __shfl_xor(p2, 4, 64);
    p2 += __shfl_xor(p2, 8, 64);                   // reduce over r (g's identical)
    const float tsum = p2;

    const float inner = tsum - s0 * s0;
    const float coef = 1.0f / sqrtf(fmaxf(fabsf(inner), 1e-6f));
    const float h20 = coef * s0;

    // hyp_act = exp_map_zero(relu(log_map_zero(h2)))
    const float dist = arcosh_f(h20);
    const float tsq = coef * coef * tsum;
    const float scl = dist / sqrtf(fmaxf(tsq, 1e-6f));

    float uu[8];
    float p3 = 0.0f;
    #pragma unroll
    for (int j = 0; j < 8; ++j) {
        uu[j] = fmaxf(scl * coef * sf[j], 0.0f);
        p3 = fmaf(uu[j], uu[j], p3);
    }
    p3 += __shfl_xor(p3, 1, 64);
    p3 += __shfl_xor(p3, 2, 64);
    p3 += __shfl_xor(p3, 4, 64);
    p3 += __shfl_xor(p3, 8, 64);
    const float S = p3;
    const float n = sqrtf(fmaxf(S, 1e-6f));
    const float rr = sinhf(fminf(n, 50.0f)) / n;

    // lane l writes comps c1 = r*8+2g, c2 = c1+1 (c2==127 -> head to out[0])
    const float ua = (g < 2) ? ((g == 0) ? uu[0] : uu[2]) : ((g == 2) ? uu[4] : uu[6]);
    const float ub = (g < 2) ? ((g == 0) ? uu[1] : uu[3]) : ((g == 2) ? uu[5] : uu[7]);
    const int c1 = r * 8 + 2 * g;
    float* op = out + (long)node * 128;
    op[1 + c1] = rr * ua;
    if (c1 + 1 < 127) op[2 + c1] = rr * ub;
    else              op[0] = sqrtf(1.0f + rr * rr * S);   // lane 63
}

extern "C" void kernel_launch(void* const* d_in, const int* in_sizes, int n_in,
                              void* d_out, int out_size, void* d_ws, size_t ws_size,
                              hipStream_t stream) {
    const float* x       = (const float*)d_in[0];
    const float* weight  = (const float*)d_in[1];
    const float* bias    = (const float*)d_in[2];
    const float* adj_val = (const float*)d_in[3];
    const int*   adj_row = (const int*)d_in[4];
    const int*   adj_col = (const int*)d_in[5];
    float* out = (float*)d_out;

    char* ws = (char*)d_ws;
    ushort* hhb    = (ushort*)ws;                   // 12,800,000 B
    float*  hhead  = (float*)(ws + 12800000);       // 200,000 B
    int*    rowptr = (int*)(ws + 13000000);         // 200,004 B
    ushort* WfHi   = (ushort*)(ws + 13200192);      // 32,768 B
    ushort* WfLo   = (ushort*)(ws + 13232960);      // 32,768 B
    float*  biasP  = (float*)(ws + 13265728);       // 512 B

    prep_kernel<<<8, 256, 0, stream>>>(weight, bias, WfHi, WfLo, biasP);
    rowptr_kernel<<<(NE + 255) / 256, 256, 0, stream>>>(adj_row, rowptr);
    transform_kernel<<<(NN + 63) / 64, 256, 0, stream>>>(x, WfHi, biasP, hhb, hhead);
    centroid_act_kernel<<<NN / 4, 256, 0, stream>>>(hhb, hhead, adj_val, adj_col, rowptr, out);
}

// Round 15
// 69.805 us; speedup vs baseline: 1.1400x; 1.1400x over previous
//
#include <hip/hip_runtime.h>
#include <hip/hip_bf16.h>

#define NN 50000
#define NE 800000

typedef __attribute__((ext_vector_type(4))) float f32x4;
typedef __attribute__((ext_vector_type(8))) __bf16 bf16x8;

__device__ __forceinline__ float wred64(float v) {
    v += __shfl_xor(v, 32, 64);
    v += __shfl_xor(v, 16, 64);
    v += __shfl_xor(v, 8, 64);
    v += __shfl_xor(v, 4, 64);
    v += __shfl_xor(v, 2, 64);
    v += __shfl_xor(v, 1, 64);
    return v;
}

__device__ __forceinline__ float arcosh_f(float z) {
    z = fmaxf(z, 1.0f + 1e-7f);
    return logf(z + sqrtf(z * z - 1.0f));
}

// ---------------------------------------------------------------------------
// Fused prep + rowptr (one launch).
// Blocks [0, 3125): rowptr[r] = first edge with row >= r (rows sorted).
// Blocks [3125, 3133): pack W^T into MFMA B-fragment order, bf16 hi/lo.
// ---------------------------------------------------------------------------
__global__ void prep_rowptr_kernel(const float* __restrict__ weight,
                                   const float* __restrict__ bias,
                                   ushort* __restrict__ WfHi, ushort* __restrict__ WfLo,
                                   float* __restrict__ biasP,
                                   const int* __restrict__ row, int* __restrict__ rowptr) {
    const int b = blockIdx.x;
    if (b < 3125) {
        int e = b * 256 + threadIdx.x;
        if (e >= NE) return;
        int r1 = row[e];
        int r0 = (e == 0) ? -1 : row[e - 1];
        for (int r = r0 + 1; r <= r1; ++r) rowptr[r] = e;
        if (e == NE - 1) {
            for (int r = r1 + 1; r <= NN; ++r) rowptr[r] = NE;
        }
    } else {
        int t8 = (b - 3125) * 256 + threadIdx.x;   // 0..2047
        int l = t8 & 63, f = t8 >> 6;
        int t = f & 3, jt = f >> 2;
        int g = l >> 4, r = l & 15;
        int col = jt * 16 + r;
        #pragma unroll
        for (int i = 0; i < 8; ++i) {
            int k = 32 * g + 8 * t + i;
            float v = (col < 127) ? weight[col * 128 + k] : 0.0f;
            __bf16 h = (__bf16)v;
            float lo = v - (float)h;
            __bf16 lb = (__bf16)lo;
            WfHi[t8 * 8 + i] = __builtin_bit_cast(unsigned short, h);
            WfLo[t8 * 8 + i] = __builtin_bit_cast(unsigned short, lb);
        }
        if (t8 < 128) biasP[t8] = (t8 < 127) ? bias[t8] : 0.0f;
    }
}

// ---------------------------------------------------------------------------
// Stage 1 via MFMA (bf16x3 compensated): h = exp_map_zero([0, W@log0(x)+b])
// Output: hhb[node][128] bf16 (slot j = tail comp j, j<127; slot 127 = 0)
//         hhead[node]    fp32 head (the precision-critical component)
// ---------------------------------------------------------------------------
__global__ __launch_bounds__(256) void transform_kernel(
        const float* __restrict__ x, const ushort* __restrict__ Wf /* hi|lo 64KB */,
        const float* __restrict__ biasP, ushort* __restrict__ hhb,
        float* __restrict__ hhead) {
    __shared__ __align__(16) ushort WF[32768];   // 64 KB: [0,16384) hi, rest lo

    const int tid = threadIdx.x;
    #pragma unroll
    for (int i = 0; i < 16; ++i)
        ((float4*)WF)[i * 256 + tid] = ((const float4*)Wf)[i * 256 + tid];

    const int lane = tid & 63, w = tid >> 6;
    const int g = lane >> 4, r = lane & 15;
    const int nodeA = blockIdx.x * 64 + w * 16 + r;   // A-fragment row

    float xv[32];
    float x0 = 1.0f;
    if (nodeA < NN) {
        const float* xp = x + (long)nodeA * 129;
        x0 = xp[0];
        __builtin_memcpy(xv, xp + 1 + 32 * g, 128);
    } else {
        #pragma unroll
        for (int i = 0; i < 32; ++i) xv[i] = 0.0f;
    }
    // input invariant: x0 = sqrt(1 + sum tail^2)  ->  ssq = x0^2 - 1
    float dist = arcosh_f(x0);
    float sc = dist / sqrtf(fmaxf(x0 * x0 - 1.0f, 1e-6f));

    bf16x8 ah[4], al[4];
    #pragma unroll
    for (int t = 0; t < 4; ++t) {
        #pragma unroll
        for (int i = 0; i < 8; ++i) {
            float v = sc * xv[8 * t + i];
            __bf16 h = (__bf16)v;
            ah[t][i] = h;
            al[t][i] = (__bf16)(v - (float)h);
        }
    }
    __syncthreads();

    f32x4 acc[8];
    #pragma unroll
    for (int jt = 0; jt < 8; ++jt) acc[jt] = (f32x4){0.0f, 0.0f, 0.0f, 0.0f};

    #pragma unroll
    for (int jt = 0; jt < 8; ++jt) {
        #pragma unroll
        for (int t = 0; t < 4; ++t) {
            const int f = jt * 4 + t;
            bf16x8 bh = *(const bf16x8*)&WF[(f * 64 + lane) * 8];
            bf16x8 bl = *(const bf16x8*)&WF[16384 + (f * 64 + lane) * 8];
            acc[jt] = __builtin_amdgcn_mfma_f32_16x16x32_bf16(al[t], bh, acc[jt], 0, 0, 0);
            acc[jt] = __builtin_amdgcn_mfma_f32_16x16x32_bf16(ah[t], bl, acc[jt], 0, 0, 0);
            acc[jt] = __builtin_amdgcn_mfma_f32_16x16x32_bf16(ah[t], bh, acc[jt], 0, 0, 0);
        }
    }

    float bv[8];
    #pragma unroll
    for (int jt = 0; jt < 8; ++jt) bv[jt] = biasP[jt * 16 + r];

    #pragma unroll
    for (int i = 0; i < 4; ++i) {
        float m[8];
        float p = 0.0f;
        #pragma unroll
        for (int jt = 0; jt < 8; ++jt) {
            m[jt] = acc[jt][i] + bv[jt];
            p = fmaf(m[jt], m[jt], p);
        }
        p += __shfl_xor(p, 1, 64);
        p += __shfl_xor(p, 2, 64);
        p += __shfl_xor(p, 4, 64);
        p += __shfl_xor(p, 8, 64);        // p = sum_{j<127} mx_j^2
        float n = sqrtf(fmaxf(p, 1e-6f));
        float rr = sinhf(fminf(n, 50.0f)) / n;
        int node = blockIdx.x * 64 + w * 16 + g * 4 + i;
        if (node < NN) {
            #pragma unroll
            for (int jt = 0; jt < 8; ++jt) {
                int j = jt * 16 + r;
                float vv = rr * m[jt];
                ushort us = (j == 127) ? (ushort)0
                          : __builtin_bit_cast(unsigned short, (__bf16)vv);
                hhb[node * 128 + j] = us;
            }
            if (r == 15) hhead[node] = sqrtf(1.0f + rr * rr * p);
        }
    }
}

// ---------------------------------------------------------------------------
// Stage 2+3 fused: segment gather-sum (bf16 rows + fp32 head), Lorentz
// centroid normalize, hyp_act. One wave per node; lane holds comps 2l,2l+1
// (slot 127 = zero pad). Instruction-minimized version of round 11:
//   - head path HOISTED out of the row loop: one pre-pass, lane l handles
//     edge lo+l (strided loop for safety; max degree << 64) -> s0 is an
//     exact unreplicated sum, and the 8-edge loop loses its select+gather
//     head block (~25% of loop instructions).
//   - row loop: 8 independent wave-wide dword gathers; col/val via uniform
//     s_loads + SALU cselect clamps; uint offset arithmetic so each gather
//     is SALU-base + loop-invariant voffset (no per-lane 64-bit chain).
//     Per edge per lane: 1 load + 2 unpack + 2 fma.
// ---------------------------------------------------------------------------
__global__ __launch_bounds__(256) void centroid_act_kernel(
        const ushort* __restrict__ hhb, const float* __restrict__ hhead,
        const float* __restrict__ val, const int* __restrict__ col,
        const int* __restrict__ rowptr, float* __restrict__ out) {
    const int lane = threadIdx.x & 63;
    const int node = __builtin_amdgcn_readfirstlane(blockIdx.x * 4 + (threadIdx.x >> 6));
    const int lo = rowptr[node], hi = rowptr[node + 1];

    // head pre-pass: one gather round for all of this node's edges
    float s0p = 0.0f;
    for (int eh = lo + lane; eh < hi; eh += 64) {
        s0p = fmaf(val[eh], hhead[col[eh]], s0p);
    }
    float s0 = wred64(s0p);                       // exact: each edge once

    // row loop
    const uint voff = 2u * (uint)lane;            // ushort index within row
    float sf0 = 0.0f, sf1 = 0.0f;
    for (int e = lo; e < hi; e += 8) {
        const int m = hi - e;                     // uniform
        int c[8]; float v[8];
        #pragma unroll
        for (int k = 0; k < 8; ++k) {
            const int ik = (k < m) ? k : (m - 1); // uniform -> s_cselect
            c[k] = col[e + ik];
            v[k] = (k < m) ? val[e + ik] : 0.0f;
        }
        uint u[8];
        #pragma unroll
        for (int k = 0; k < 8; ++k)
            u[k] = *(const uint*)&hhb[(((uint)c[k]) << 7) + voff];
        #pragma unroll
        for (int k = 0; k < 8; ++k) {
            sf0 = fmaf(v[k], __builtin_bit_cast(float, u[k] << 16), sf0);
            sf1 = fmaf(v[k], __builtin_bit_cast(float, u[k] & 0xffff0000u), sf1);
        }
    }

    // Lorentz inner = sum_tail s_f^2 - s0^2 (slot 127 pad contributes 0)
    float tsum = wred64(sf0 * sf0 + sf1 * sf1);
    float inner = tsum - s0 * s0;
    float coef = 1.0f / sqrtf(fmaxf(fabsf(inner), 1e-6f));
    float h20 = coef * s0;                        // wave-uniform

    // hyp_act = exp_map_zero(relu(log_map_zero(h2)))
    float dist = arcosh_f(h20);
    float tsq = coef * coef * tsum;               // ||h2 tail||^2, no reduce needed
    float scl = dist / sqrtf(fmaxf(tsq, 1e-6f));
    float u0 = fmaxf(scl * coef * sf0, 0.0f);
    float u1 = fmaxf(scl * coef * sf1, 0.0f);     // lane63: sf1==0 -> u1==0
    float S = wred64(u0 * u0 + u1 * u1);
    float n = sqrtf(fmaxf(S, 1e-6f));
    float r = sinhf(fminf(n, 50.0f)) / n;

    float* op = out + (long)node * 128;
    op[1 + 2 * lane] = r * u0;                        // tail c=2l -> out comp 2l+1
    if (lane < 63) op[2 + 2 * lane] = r * u1;         // tail c=2l+1 -> out comp 2l+2
    else           op[0] = sqrtf(1.0f + r * r * S);   // head
}

extern "C" void kernel_launch(void* const* d_in, const int* in_sizes, int n_in,
                              void* d_out, int out_size, void* d_ws, size_t ws_size,
                              hipStream_t stream) {
    const float* x       = (const float*)d_in[0];
    const float* weight  = (const float*)d_in[1];
    const float* bias    = (const float*)d_in[2];
    const float* adj_val = (const float*)d_in[3];
    const int*   adj_row = (const int*)d_in[4];
    const int*   adj_col = (const int*)d_in[5];
    float* out = (float*)d_out;

    char* ws = (char*)d_ws;
    ushort* hhb    = (ushort*)ws;                   // 12,800,000 B
    float*  hhead  = (float*)(ws + 12800000);       // 200,000 B
    int*    rowptr = (int*)(ws + 13000000);         // 200,004 B
    ushort* WfHi   = (ushort*)(ws + 13200192);      // 32,768 B
    ushort* WfLo   = (ushort*)(ws + 13232960);      // 32,768 B
    float*  biasP  = (float*)(ws + 13265728);       // 512 B

    prep_rowptr_kernel<<<3133, 256, 0, stream>>>(weight, bias, WfHi, WfLo, biasP,
                                                 adj_row, rowptr);
    transform_kernel<<<(NN + 63) / 64, 256, 0, stream>>>(x, WfHi, biasP, hhb, hhead);
    centroid_act_kernel<<<NN / 4, 256, 0, stream>>>(hhb, hhead, adj_val, adj_col, rowptr, out);
}